// Round 4
// baseline (518.438 us; speedup 1.0000x reference)
//
#include <hip/hip_runtime.h>
#include <hip/hip_bf16.h>
#include <cstdint>

#define DI __device__ __forceinline__

using bf16x8 = __attribute__((ext_vector_type(8))) short;
using f32x4  = __attribute__((ext_vector_type(4))) float;

constexpr int IN_DIM = 384;
constexpr int HID    = 512;
constexpr int KTOT   = IN_DIM * 20;      // 7680: k = i*20 + t; t==0 -> silu, t-1 -> spline coef c
constexpr int BM = 64, BN = 128, BK = 160;   // 8 input dims per K-step
constexpr int NSTEP = KTOT / BK;             // 48
// A rows: 336B stride (mod 128 = 80) -> 16 row-starts cycle all 8 16B slots: conflict-free
// ds_read_b128. A is written by plain ds_write so any stride is legal.
// B rows: 320B linear -- REQUIRED by global_load_lds (wave-uniform base + lane*16; no
// predication allowed: base comes from first ACTIVE lane -- R3's padded variant broke this).
constexpr int A_STRIDE_B = 336;
constexpr int B_STRIDE_B = 320;

DI unsigned short f2bf(float f) {
  union { float f; uint32_t u; } v; v.f = f;
  uint32_t r = (v.u + 0x7FFFu + ((v.u >> 16) & 1u)) >> 16;
  return (unsigned short)r;
}
DI float fast_tanh(float x) {
  float e = __expf(2.0f * x);
  return 1.0f - 2.0f / (e + 1.0f);
}
// row-XOR swizzle for 1024B-stride LDS tiles (kfinal weight tile)
DI uint32_t swzw(uint32_t L) { return L ^ ((L >> 6) & 0x70u); }

#define GLOAD_LDS16(g, l)                                                        \
  __builtin_amdgcn_global_load_lds((const __attribute__((address_space(1))) void*)(g), \
                                   (__attribute__((address_space(3))) void*)(l), 16, 0, 0)

// ---------------- pack base_weight + spline_weight -> bf16 W[o][k], k = i*20 + t ----------------
__global__ __launch_bounds__(256) void kpack(const float* __restrict__ bw,
                                             const float* __restrict__ sw,
                                             unsigned short* __restrict__ Wb) {
  int idx = blockIdx.x * 256 + threadIdx.x;      // idx = o*384 + i ; W offset = idx*20
  const float* s = sw + (size_t)idx * 19;
  unsigned short* d = Wb + (size_t)idx * 20;
  d[0] = f2bf(bw[idx]);
#pragma unroll
  for (int c = 0; c < 19; ++c) d[1 + c] = f2bf(s[c]);
}

// ---------------- fused KAN GEMM: h[b][o] = tanh( A(x) @ W^T ) ----------------
__global__ __launch_bounds__(256) void kgemm1(const float* __restrict__ z,
                                              const float* __restrict__ ms,
                                              const float* __restrict__ md,
                                              const unsigned short* __restrict__ Wb,
                                              unsigned short* __restrict__ hout) {
  __shared__ char ldsbuf[64 * A_STRIDE_B + 128 * B_STRIDE_B];   // 21504 + 40960 = 62464B
  char* AsB = ldsbuf;
  char* BsB = ldsbuf + 64 * A_STRIDE_B;

  const int tid  = threadIdx.x;
  const int lane = tid & 63;
  const int wv   = tid >> 6;                 // 0..3 (waves tile N)
  const int l16  = lane & 15;
  const int lhi  = lane >> 4;                // 0..3

  // XCD-aware swizzle: grid 2048 = 8*256; nblk locality within XCD -> W slice L2-resident
  int wg = blockIdx.x;
  int id = (wg & 7) * 256 + (wg >> 3);
  const int mblk = id & 511;
  const int nblk = id >> 9;
  const int row0 = mblk * BM;
  const int col0 = nblk * BN;

  f32x4 acc[4][2] = {};

  for (int s = 0; s < NSTEP; ++s) {
    // ---- stage B: 128 rows x 320B = 2560 16B chunks, async global->LDS, fully active waves
#pragma unroll
    for (int rr = 0; rr < 10; ++rr) {
      int chunk = rr * 256 + tid;
      int o  = chunk / 20;
      int sl = chunk - o * 20;
      const unsigned short* g = Wb + (size_t)(col0 + o) * KTOT + s * BK + sl * 8;
      GLOAD_LDS16(g, BsB + chunk * 16);
    }
    // ---- stage A: generate 64 rows x 8 input dims, 20 entries each (silu + 4 nonzero bases)
#pragma unroll
    for (int r = 0; r < 2; ++r) {
      int task = tid + r * 256;              // 512 tasks
      int arow = task >> 3;                  // 0..63
      int isl  = task & 7;                   // 0..7
      int i    = s * 8 + isl;                // global input dim
      const float* src = (i < 128) ? z : (i < 256 ? ms : md);
      float x  = src[(size_t)(row0 + arow) * 128 + (i & 127)];
      float xt = fast_tanh(x);
      float tt = (xt + 1.0f) * 8.0f;         // in [0,16]
      int   m  = (int)tt; m = m > 16 ? 16 : m;
      float u  = tt - (float)m;
      float omu = 1.0f - u;
      float u2 = u * u, u3 = u2 * u;
      float w0 = omu * omu * omu * (1.0f / 6.0f);
      float w1 = (3.0f * u3 - 6.0f * u2 + 4.0f) * (1.0f / 6.0f);
      float w2 = (-3.0f * u3 + 3.0f * u2 + 3.0f * u + 1.0f) * (1.0f / 6.0f);
      float w3 = u3 * (1.0f / 6.0f);
      float sil = xt / (1.0f + __expf(-xt));
      uint32_t base = (uint32_t)arow * A_STRIDE_B + isl * 40;
#pragma unroll
      for (int zz = 0; zz < 5; ++zz)
        *(uint64_t*)(AsB + base + zz * 8) = 0ull;
      *(short*)(AsB + base) = (short)f2bf(sil);                 // t = 0
      *(short*)(AsB + base + 2u * (m + 1)) = (short)f2bf(w0);   // c = m
      *(short*)(AsB + base + 2u * (m + 2)) = (short)f2bf(w1);
      *(short*)(AsB + base + 2u * (m + 3)) = (short)f2bf(w2);
      if (m < 16)                                                // c = m+3 (drop c==19)
        *(short*)(AsB + base + 2u * (m + 4)) = (short)f2bf(w3);
    }
    __syncthreads();
    // ---- compute: 5 K-sub-steps of 32
    const uint32_t bbase = (uint32_t)(wv * 32) * B_STRIDE_B;
#pragma unroll
    for (int ks = 0; ks < 5; ++ks) {
      bf16x8 af[4], bfr[2];
#pragma unroll
      for (int mi = 0; mi < 4; ++mi) {
        uint32_t L = (uint32_t)(mi * 16 + l16) * A_STRIDE_B + ks * 64 + lhi * 16;
        af[mi] = *(const bf16x8*)(AsB + L);
      }
#pragma unroll
      for (int ni = 0; ni < 2; ++ni) {
        uint32_t L = bbase + (uint32_t)(ni * 16 + l16) * B_STRIDE_B + ks * 64 + lhi * 16;
        bfr[ni] = *(const bf16x8*)(BsB + L);
      }
#pragma unroll
      for (int mi = 0; mi < 4; ++mi)
#pragma unroll
        for (int ni = 0; ni < 2; ++ni)
          acc[mi][ni] = __builtin_amdgcn_mfma_f32_16x16x32_bf16(af[mi], bfr[ni], acc[mi][ni], 0, 0, 0);
    }
    __syncthreads();
  }
  // ---- epilogue: tanh -> bf16 h
#pragma unroll
  for (int mi = 0; mi < 4; ++mi)
#pragma unroll
    for (int ni = 0; ni < 2; ++ni)
#pragma unroll
      for (int rg = 0; rg < 4; ++rg) {
        int grow = row0 + mi * 16 + lhi * 4 + rg;
        int gcol = col0 + wv * 32 + ni * 16 + l16;
        hout[(size_t)grow * HID + gcol] = f2bf(fast_tanh(acc[mi][ni][rg]));
      }
}

// ---------------- kfinal (MFMA): 64 rows/block, all 64 output cols ----------------
__global__ __launch_bounds__(256) void kfinal(const unsigned short* __restrict__ h,
                                              const float* __restrict__ lw,
                                              const float* __restrict__ lb,
                                              float* __restrict__ out) {
  __shared__ unsigned short Ws[64 * 512];    // 64 KiB, rows 1024B, XOR-swizzled via swzw()
  char* WsB = (char*)Ws;
  const int tid  = threadIdx.x;
  const int lane = tid & 63;
  const int wv   = tid >> 6;                 // wave -> 16-row strip
  const int l16  = lane & 15;
  const int lhi  = lane >> 4;
  const int row0 = blockIdx.x * 64;

  // stage lin_w [64][512] fp32 -> bf16 LDS
#pragma unroll
  for (int it = 0; it < 16; ++it) {
    int c = it * 256 + tid;
    int r = c >> 6;
    int k8 = (c & 63) * 8;
    const float* g = lw + r * 512 + k8;
    float4 f0 = *(const float4*)g;
    float4 f1 = *(const float4*)(g + 4);
    union { unsigned short s[8]; bf16x8 v; } u;
    u.s[0] = f2bf(f0.x); u.s[1] = f2bf(f0.y); u.s[2] = f2bf(f0.z); u.s[3] = f2bf(f0.w);
    u.s[4] = f2bf(f1.x); u.s[5] = f2bf(f1.y); u.s[6] = f2bf(f1.z); u.s[7] = f2bf(f1.w);
    *(bf16x8*)(WsB + swzw((uint32_t)r * 1024u + (uint32_t)k8 * 2u)) = u.v;
  }
  __syncthreads();

  const int arow = row0 + wv * 16 + l16;
  const unsigned short* ag = h + (size_t)arow * HID + lhi * 8;
  f32x4 acc[4] = {};
#pragma unroll
  for (int ks = 0; ks < 16; ++ks) {
    bf16x8 af = *(const bf16x8*)(ag + ks * 32);
#pragma unroll
    for (int ni = 0; ni < 4; ++ni) {
      uint32_t L = (uint32_t)(ni * 16 + l16) * 1024u + (uint32_t)(ks * 64 + lhi * 16);
      bf16x8 bfr = *(const bf16x8*)(WsB + swzw(L));
      acc[ni] = __builtin_amdgcn_mfma_f32_16x16x32_bf16(af, bfr, acc[ni], 0, 0, 0);
    }
  }
#pragma unroll
  for (int ni = 0; ni < 4; ++ni) {
    int col = ni * 16 + l16;
    float bias = lb[col];
#pragma unroll
    for (int rg = 0; rg < 4; ++rg) {
      int grow = row0 + wv * 16 + lhi * 4 + rg;
      out[(size_t)grow * 64 + col] = acc[ni][rg] + bias;
    }
  }
}

extern "C" void kernel_launch(void* const* d_in, const int* in_sizes, int n_in,
                              void* d_out, int out_size, void* d_ws, size_t ws_size,
                              hipStream_t stream) {
  const float* z  = (const float*)d_in[0];
  const float* ms = (const float*)d_in[1];
  const float* md = (const float*)d_in[2];
  const float* bw = (const float*)d_in[3];
  const float* sw = (const float*)d_in[4];
  const float* lw = (const float*)d_in[5];
  const float* lb = (const float*)d_in[6];
  float* out = (float*)d_out;

  unsigned short* Wb = (unsigned short*)d_ws;                        // 7.5 MiB: bf16 W [512][7680]
  unsigned short* hb = (unsigned short*)((char*)d_ws + (8u << 20));  // 32 MiB: bf16 h [32768][512]

  kpack<<<(HID * IN_DIM) / 256, 256, 0, stream>>>(bw, sw, Wb);
  kgemm1<<<2048, 256, 0, stream>>>(z, ms, md, Wb, hb);
  kfinal<<<32768 / 64, 256, 0, stream>>>(hb, lw, lb, out);
}

// Round 5
// 411.517 us; speedup vs baseline: 1.2598x; 1.2598x over previous
//
#include <hip/hip_runtime.h>
#include <hip/hip_bf16.h>
#include <cstdint>

#define DI __device__ __forceinline__

using bf16x8 = __attribute__((ext_vector_type(8))) short;
using f32x4  = __attribute__((ext_vector_type(4))) float;

constexpr int IN_DIM = 384;
constexpr int HID    = 512;
constexpr int KTOT   = IN_DIM * 20;      // 7680: k = i*20 + t; t==0 -> silu, t-1 -> spline coef c
constexpr int BM = 256, BN = 128, BK = 160;  // 8 input dims per K-step
constexpr int NSTEP = KTOT / BK;             // 48
// A rows: 336B stride (mod 128 = 80) -> 16 row-starts cycle all 8 16B slots: conflict-free
// ds_read_b128 (plain ds_write side, any stride legal).
// B rows: 320B linear -- REQUIRED by global_load_lds (wave-uniform base + lane*16, no
// predication: R3 lesson).
constexpr int A_STRIDE_B = 336;
constexpr int B_STRIDE_B = 320;
constexpr int LDS_BYTES  = BM * A_STRIDE_B + BN * B_STRIDE_B;   // 86016 + 40960 = 126976

DI unsigned short f2bf(float f) {
  union { float f; uint32_t u; } v; v.f = f;
  uint32_t r = (v.u + 0x7FFFu + ((v.u >> 16) & 1u)) >> 16;
  return (unsigned short)r;
}
DI float fast_tanh(float x) {
  float e = __expf(2.0f * x);
  return 1.0f - 2.0f / (e + 1.0f);
}
// row-XOR swizzle for 1024B-stride LDS tiles (kfinal weight tile)
DI uint32_t swzw(uint32_t L) { return L ^ ((L >> 6) & 0x70u); }

#define GLOAD_LDS16(g, l)                                                        \
  __builtin_amdgcn_global_load_lds((const __attribute__((address_space(1))) void*)(g), \
                                   (__attribute__((address_space(3))) void*)(l), 16, 0, 0)

// ---------------- pack base_weight + spline_weight -> bf16 W[o][k], k = i*20 + t ----------------
__global__ __launch_bounds__(256) void kpack(const float* __restrict__ bw,
                                             const float* __restrict__ sw,
                                             unsigned short* __restrict__ Wb) {
  int idx = blockIdx.x * 256 + threadIdx.x;      // idx = o*384 + i ; W offset = idx*20
  const float* s = sw + (size_t)idx * 19;
  unsigned short* d = Wb + (size_t)idx * 20;
  d[0] = f2bf(bw[idx]);
#pragma unroll
  for (int c = 0; c < 19; ++c) d[1 + c] = f2bf(s[c]);
}

// ---------------- fused KAN GEMM: h[b][o] = tanh( A(x) @ W^T ) ----------------
// 512 threads = 8 waves, wave grid 4(M) x 2(N), wave tile 64x64, acc[4][4].
__global__ __launch_bounds__(512, 2) void kgemm1(const float* __restrict__ z,
                                                 const float* __restrict__ ms,
                                                 const float* __restrict__ md,
                                                 const unsigned short* __restrict__ Wb,
                                                 unsigned short* __restrict__ hout) {
  extern __shared__ char ldsbuf[];            // 124 KiB dynamic
  char* AsB = ldsbuf;
  char* BsB = ldsbuf + BM * A_STRIDE_B;

  const int tid  = threadIdx.x;
  const int lane = tid & 63;
  const int wv   = tid >> 6;                 // 0..7
  const int wr   = wv >> 1;                  // 0..3 : M strip
  const int wc   = wv & 1;                   // 0..1 : N strip
  const int l16  = lane & 15;
  const int lhi  = lane >> 4;                // 0..3

  // XCD-aware bijective swizzle: grid 512 = 8 XCD * 64; 2 XCDs share one nblk (2MB W slice)
  int wg = blockIdx.x;
  int id = (wg & 7) * 64 + (wg >> 3);
  const int mblk = id & 127;
  const int nblk = id >> 7;
  const int row0 = mblk * BM;
  const int col0 = nblk * BN;

  f32x4 acc[4][4] = {};

  for (int s = 0; s < NSTEP; ++s) {
    // ---- stage B: 128 rows x 320B = 2560 16B chunks over 512 threads, async global->LDS
#pragma unroll
    for (int rr = 0; rr < 5; ++rr) {
      int chunk = rr * 512 + tid;
      int o  = chunk / 20;
      int sl = chunk - o * 20;
      const unsigned short* g = Wb + (size_t)(col0 + o) * KTOT + s * BK + sl * 8;
      GLOAD_LDS16(g, BsB + chunk * 16);
    }
    // ---- stage A: 256 rows x 8 dims = 2048 tasks over 512 threads
#pragma unroll
    for (int r = 0; r < 4; ++r) {
      int task = tid + r * 512;
      int arow = task >> 3;                  // 0..255
      int isl  = task & 7;                   // 0..7
      int i    = s * 8 + isl;                // global input dim
      const float* src = (i < 128) ? z : (i < 256 ? ms : md);
      float x  = src[(size_t)(row0 + arow) * 128 + (i & 127)];
      float xt = fast_tanh(x);
      float tt = (xt + 1.0f) * 8.0f;         // in [0,16]
      int   m  = (int)tt; m = m > 16 ? 16 : m;
      float u  = tt - (float)m;
      float omu = 1.0f - u;
      float u2 = u * u, u3 = u2 * u;
      float w0 = omu * omu * omu * (1.0f / 6.0f);
      float w1 = (3.0f * u3 - 6.0f * u2 + 4.0f) * (1.0f / 6.0f);
      float w2 = (-3.0f * u3 + 3.0f * u2 + 3.0f * u + 1.0f) * (1.0f / 6.0f);
      float w3 = u3 * (1.0f / 6.0f);
      float sil = xt / (1.0f + __expf(-xt));
      uint32_t base = (uint32_t)arow * A_STRIDE_B + isl * 40;
#pragma unroll
      for (int zz = 0; zz < 5; ++zz)
        *(uint64_t*)(AsB + base + zz * 8) = 0ull;
      *(short*)(AsB + base) = (short)f2bf(sil);                 // t = 0
      *(short*)(AsB + base + 2u * (m + 1)) = (short)f2bf(w0);   // c = m
      *(short*)(AsB + base + 2u * (m + 2)) = (short)f2bf(w1);
      *(short*)(AsB + base + 2u * (m + 3)) = (short)f2bf(w2);
      if (m < 16)                                                // c = m+3 (drop c==19)
        *(short*)(AsB + base + 2u * (m + 4)) = (short)f2bf(w3);
    }
    __syncthreads();                          // drains vmcnt (DMA) + lgkm (ds_write)
    // ---- compute: 5 K-sub-steps of 32; wave tile 64x64
#pragma unroll
    for (int ks = 0; ks < 5; ++ks) {
      bf16x8 af[4], bfr[4];
#pragma unroll
      for (int mi = 0; mi < 4; ++mi) {
        uint32_t L = (uint32_t)(wr * 64 + mi * 16 + l16) * A_STRIDE_B + ks * 64 + lhi * 16;
        af[mi] = *(const bf16x8*)(AsB + L);
      }
#pragma unroll
      for (int ni = 0; ni < 4; ++ni) {
        uint32_t L = (uint32_t)(wc * 64 + ni * 16 + l16) * B_STRIDE_B + ks * 64 + lhi * 16;
        bfr[ni] = *(const bf16x8*)(BsB + L);
      }
#pragma unroll
      for (int mi = 0; mi < 4; ++mi)
#pragma unroll
        for (int ni = 0; ni < 4; ++ni)
          acc[mi][ni] = __builtin_amdgcn_mfma_f32_16x16x32_bf16(af[mi], bfr[ni], acc[mi][ni], 0, 0, 0);
    }
    __syncthreads();                          // protect LDS from next stage overwrite
  }
  // ---- epilogue: tanh -> bf16 h
#pragma unroll
  for (int mi = 0; mi < 4; ++mi)
#pragma unroll
    for (int ni = 0; ni < 4; ++ni)
#pragma unroll
      for (int rg = 0; rg < 4; ++rg) {
        int grow = row0 + wr * 64 + mi * 16 + lhi * 4 + rg;
        int gcol = col0 + wc * 64 + ni * 16 + l16;
        hout[(size_t)grow * HID + gcol] = f2bf(fast_tanh(acc[mi][ni][rg]));
      }
}

// ---------------- kfinal (MFMA): 64 rows/block, all 64 output cols ----------------
__global__ __launch_bounds__(256) void kfinal(const unsigned short* __restrict__ h,
                                              const float* __restrict__ lw,
                                              const float* __restrict__ lb,
                                              float* __restrict__ out) {
  __shared__ unsigned short Ws[64 * 512];    // 64 KiB, rows 1024B, XOR-swizzled via swzw()
  char* WsB = (char*)Ws;
  const int tid  = threadIdx.x;
  const int lane = tid & 63;
  const int wv   = tid >> 6;                 // wave -> 16-row strip
  const int l16  = lane & 15;
  const int lhi  = lane >> 4;
  const int row0 = blockIdx.x * 64;

  // stage lin_w [64][512] fp32 -> bf16 LDS
#pragma unroll
  for (int it = 0; it < 16; ++it) {
    int c = it * 256 + tid;
    int r = c >> 6;
    int k8 = (c & 63) * 8;
    const float* g = lw + r * 512 + k8;
    float4 f0 = *(const float4*)g;
    float4 f1 = *(const float4*)(g + 4);
    union { unsigned short s[8]; bf16x8 v; } u;
    u.s[0] = f2bf(f0.x); u.s[1] = f2bf(f0.y); u.s[2] = f2bf(f0.z); u.s[3] = f2bf(f0.w);
    u.s[4] = f2bf(f1.x); u.s[5] = f2bf(f1.y); u.s[6] = f2bf(f1.z); u.s[7] = f2bf(f1.w);
    *(bf16x8*)(WsB + swzw((uint32_t)r * 1024u + (uint32_t)k8 * 2u)) = u.v;
  }
  __syncthreads();

  const int arow = row0 + wv * 16 + l16;
  const unsigned short* ag = h + (size_t)arow * HID + lhi * 8;
  f32x4 acc[4] = {};
#pragma unroll
  for (int ks = 0; ks < 16; ++ks) {
    bf16x8 af = *(const bf16x8*)(ag + ks * 32);
#pragma unroll
    for (int ni = 0; ni < 4; ++ni) {
      uint32_t L = (uint32_t)(ni * 16 + l16) * 1024u + (uint32_t)(ks * 64 + lhi * 16);
      bf16x8 bfr = *(const bf16x8*)(WsB + swzw(L));
      acc[ni] = __builtin_amdgcn_mfma_f32_16x16x32_bf16(af, bfr, acc[ni], 0, 0, 0);
    }
  }
#pragma unroll
  for (int ni = 0; ni < 4; ++ni) {
    int col = ni * 16 + l16;
    float bias = lb[col];
#pragma unroll
    for (int rg = 0; rg < 4; ++rg) {
      int grow = row0 + wv * 16 + lhi * 4 + rg;
      out[(size_t)grow * 64 + col] = acc[ni][rg] + bias;
    }
  }
}

extern "C" void kernel_launch(void* const* d_in, const int* in_sizes, int n_in,
                              void* d_out, int out_size, void* d_ws, size_t ws_size,
                              hipStream_t stream) {
  const float* z  = (const float*)d_in[0];
  const float* ms = (const float*)d_in[1];
  const float* md = (const float*)d_in[2];
  const float* bw = (const float*)d_in[3];
  const float* sw = (const float*)d_in[4];
  const float* lw = (const float*)d_in[5];
  const float* lb = (const float*)d_in[6];
  float* out = (float*)d_out;

  unsigned short* Wb = (unsigned short*)d_ws;                        // 7.5 MiB: bf16 W [512][7680]
  unsigned short* hb = (unsigned short*)((char*)d_ws + (8u << 20));  // 32 MiB: bf16 h [32768][512]

  // allow >64KB dynamic LDS (124 KiB); idempotent host-side config, graph-capture-safe
  hipFuncSetAttribute((const void*)kgemm1,
                      hipFuncAttributeMaxDynamicSharedMemorySize, LDS_BYTES);

  kpack<<<(HID * IN_DIM) / 256, 256, 0, stream>>>(bw, sw, Wb);
  kgemm1<<<512, 512, LDS_BYTES, stream>>>(z, ms, md, Wb, hb);
  kfinal<<<32768 / 64, 256, 0, stream>>>(hb, lw, lb, out);
}